// Round 2
// baseline (835.540 us; speedup 1.0000x reference)
//
#include <hip/hip_runtime.h>
#include <hip/hip_bf16.h>

#define NJ 24
#define NV 6890
#define NB 1024
#define NVP 6912          // NV padded to 108*64
#define KP 224            // K padded: 207 pose + 10 betas + 1 template + 6 zero
#define V3 (NV*3)         // 20670 floats per batch in out
#define JTR_OFF (NB*NV*3)

typedef __attribute__((ext_vector_type(8))) short bf16x8;
typedef __attribute__((ext_vector_type(4))) float f32x4;

__constant__ int c_par[NJ] = {-1,0,0,0,1,2,3,4,5,6,7,8,9,9,9,12,13,14,16,17,18,19,20,21};

// ---------------------------------------------------------------------------
// k0: fold joint regressor: Jc[j][c][s], s<10: Jreg@shapedirs, s=10: Jreg@tmpl
// ---------------------------------------------------------------------------
__global__ void k0(const float* __restrict__ Jreg, const float* __restrict__ vtempl,
                   const float* __restrict__ shdirs, float* __restrict__ Jc)
{
    int j = blockIdx.x;
    float acc[33];
#pragma unroll
    for (int i = 0; i < 33; ++i) acc[i] = 0.0f;

    for (int v = blockIdx.y * 256 + threadIdx.x; v < NV; v += 1024) {
        float r = Jreg[j * NV + v];
#pragma unroll
        for (int c = 0; c < 3; ++c) {
            acc[c * 11 + 10] += r * vtempl[v * 3 + c];
            const float* sd = &shdirs[(v * 3 + c) * 10];
#pragma unroll
            for (int s = 0; s < 10; ++s) acc[c * 11 + s] += r * sd[s];
        }
    }
#pragma unroll
    for (int i = 0; i < 33; ++i) {
        float x = acc[i];
        for (int o = 32; o > 0; o >>= 1) x += __shfl_down(x, o, 64);
        acc[i] = x;
    }
    __shared__ float red[4][33];
    int w = threadIdx.x >> 6, l = threadIdx.x & 63;
    if (l == 0) {
#pragma unroll
        for (int i = 0; i < 33; ++i) red[w][i] = acc[i];
    }
    __syncthreads();
    if (threadIdx.x < 33) {
        float s = red[0][threadIdx.x] + red[1][threadIdx.x] +
                  red[2][threadIdx.x] + red[3][threadIdx.x];
        atomicAdd(&Jc[j * 33 + threadIdx.x], s);
    }
}

// ---------------------------------------------------------------------------
// kpack: build pdB_sw (bf16), pre-swizzled to the k2g LDS image order:
//   chunk cid = (((vtile*7 + kt)*3 + c)*4 + kq)*64 + v64 ; each chunk = 8 k.
//   row m = c-planar vertex, K = [pose 207 | betas 10 | tmpl 1 | 0 x6]
// ---------------------------------------------------------------------------
__global__ void kpack(const float* __restrict__ pdirs, const float* __restrict__ shdirs,
                      const float* __restrict__ vtempl, __hip_bfloat16* __restrict__ pdBsw)
{
    int cid = blockIdx.x * 256 + threadIdx.x;   // < 580608
    int v64 = cid & 63;
    int t = cid >> 6;
    int kq = t & 3; t >>= 2;
    int c = t % 3; t /= 3;
    int kt = t % 7;
    int vt = t / 7;
    int v = vt * 64 + v64;

    ushort tmp[8] __attribute__((aligned(16)));
#pragma unroll
    for (int j = 0; j < 8; ++j) {
        int k = kt * 32 + kq * 8 + j;
        float val = 0.0f;
        if (v < NV) {
            if (k < 207)       val = pdirs[(v * 3 + c) * 207 + k];
            else if (k < 217)  val = shdirs[(v * 3 + c) * 10 + (k - 207)];
            else if (k == 217) val = vtempl[v * 3 + c];
        }
        __hip_bfloat16 h = __float2bfloat16(val);
        tmp[j] = *(ushort*)&h;
    }
    ((float4*)pdBsw)[cid] = *(const float4*)tmp;
}

// kw: wtsT[j][v] = weights[v][j], zero-padded to NVP
__global__ void kw(const float* __restrict__ wts, float* __restrict__ wtsT)
{
    int t = blockIdx.x * 256 + threadIdx.x;     // < 24*6912
    int j = t / NVP, v = t - j * NVP;
    wtsT[t] = (v < NV) ? wts[v * NJ + j] : 0.0f;
}

// ---------------------------------------------------------------------------
// k1: Rodrigues, A (bf16, swizzled), th_j, kinematic chain, G4[b][j][3][4],
//     th_jtr. One wave per batch, 4 batches/block.
// ABsw chunk: ((btile*7 + kt)*4 + kq)*64 + b64, 8 k each.
// ---------------------------------------------------------------------------
__device__ __forceinline__ void writeA(__hip_bfloat16* ABsw, int b, int k, float val)
{
    int btile = b >> 6, b6 = b & 63, kt = k >> 5, kq = (k >> 3) & 3, j = k & 7;
    __hip_bfloat16 h = __float2bfloat16(val);
    ABsw[((((btile * 7) + kt) * 4 + kq) * 64 + b6) * 8 + j] = h;
}

__global__ void k1(const float* __restrict__ pose, const float* __restrict__ betas,
                   const float* __restrict__ trans, const float* __restrict__ Jc,
                   __hip_bfloat16* __restrict__ ABsw, float* __restrict__ G4,
                   float* __restrict__ out)
{
    __shared__ float rots[4][NJ][9];
    __shared__ float thj [4][NJ][3];
    __shared__ float res [4][NJ][16];

    int w = threadIdx.x >> 6;
    int l = threadIdx.x & 63;
    int b = blockIdx.x * 4 + w;

    if (l < NJ) {
        int j = l;
        float ax = pose[b * 72 + j * 3 + 0];
        float ay = pose[b * 72 + j * 3 + 1];
        float az = pose[b * 72 + j * 3 + 2];
        float theta = sqrtf(ax * ax + ay * ay + az * az + 1e-8f);
        float inv = 1.0f / theta;
        float kx = ax * inv, ky = ay * inv, kz = az * inv;
        float c = cosf(theta), s = sinf(theta), mc = 1.0f - c;
        float R[9];
        R[0] = 1.0f - mc * (ky * ky + kz * kz);
        R[1] = -s * kz + mc * (kx * ky);
        R[2] =  s * ky + mc * (kx * kz);
        R[3] =  s * kz + mc * (kx * ky);
        R[4] = 1.0f - mc * (kx * kx + kz * kz);
        R[5] = -s * kx + mc * (ky * kz);
        R[6] = -s * ky + mc * (kx * kz);
        R[7] =  s * kx + mc * (ky * kz);
        R[8] = 1.0f - mc * (kx * kx + ky * ky);
#pragma unroll
        for (int e = 0; e < 9; ++e) rots[w][j][e] = R[e];
        if (j >= 1) {
            int base = (j - 1) * 9;
#pragma unroll
            for (int e = 0; e < 9; ++e) {
                float val = R[e] - ((e == 0 || e == 4 || e == 8) ? 1.0f : 0.0f);
                writeA(ABsw, b, base + e, val);
            }
        }
#pragma unroll
        for (int c3 = 0; c3 < 3; ++c3) {
            float acc = Jc[(j * 3 + c3) * 11 + 10];
#pragma unroll
            for (int s10 = 0; s10 < 10; ++s10)
                acc += Jc[(j * 3 + c3) * 11 + s10] * betas[b * 10 + s10];
            thj[w][j][c3] = acc;
        }
    } else if (l < 41) {
        int k = 207 + (l - 24);
        float val;
        if (l < 34)       val = betas[b * 10 + (l - 24)];
        else if (l == 34) val = 1.0f;
        else              val = 0.0f;
        writeA(ABsw, b, k, val);
    }
    __syncthreads();

    if (l < 16) {
        int m = l >> 2, n = l & 3;
        float v;
        if (m < 3) v = (n < 3) ? rots[w][0][m * 3 + n] : thj[w][0][m];
        else       v = (n == 3) ? 1.0f : 0.0f;
        res[w][0][l] = v;
    }
    __syncthreads();
#pragma unroll
    for (int i = 1; i < NJ; ++i) {
        int p = c_par[i];
        if (l < 16) {
            int m = l >> 2, n = l & 3;
            float acc = 0.0f;
#pragma unroll
            for (int k3 = 0; k3 < 3; ++k3) {
                float relkn = (n < 3) ? rots[w][i][k3 * 3 + n]
                                      : (thj[w][i][k3] - thj[w][p][k3]);
                acc += res[w][p][m * 4 + k3] * relkn;
            }
            if (n == 3) acc += res[w][p][m * 4 + 3];
            res[w][i][l] = acc;
        }
        __syncthreads();
    }

    if (l < NJ) {
        int j = l;
#pragma unroll
        for (int c3 = 0; c3 < 3; ++c3)
            out[JTR_OFF + b * 72 + j * 3 + c3] = res[w][j][c3 * 4 + 3] + trans[b * 3 + c3];
    }
    // G2[b][j][m][n]: cols 0..2 = G, col 3 = G.t - G.R @ thj
    for (int k = l; k < 288; k += 64) {
        int j = k / 12, m = (k % 12) >> 2, n = k & 3;
        float v;
        if (n < 3) v = res[w][j][m * 4 + n];
        else v = res[w][j][m * 4 + 3] - (res[w][j][m * 4 + 0] * thj[w][j][0] +
                                         res[w][j][m * 4 + 1] * thj[w][j][1] +
                                         res[w][j][m * 4 + 2] * thj[w][j][2]);
        G4[b * 288 + k] = v;
    }
}

// ---------------------------------------------------------------------------
// k2g: MFMA GEMM. vph[m = c*NVP+v][n = b] = pd @ A.  Block: 64v x 64b x 3c,
// 4 waves (2x2), wave 32x32 per c.  K-loop 7 x BK32, mfma 16x16x32 bf16.
// Writes v_posed into d_out as per-b c-planar: out[b*V3 + c*NV + v].
// ---------------------------------------------------------------------------
__launch_bounds__(256, 3)
__global__ void k2g(const __hip_bfloat16* __restrict__ pdBsw,
                    const __hip_bfloat16* __restrict__ ABsw,
                    float* __restrict__ outp)
{
    __shared__ ushort As[3 * 4 * 64 * 8] __attribute__((aligned(16)));  // 12 KB
    __shared__ ushort Bs[4 * 64 * 8]     __attribute__((aligned(16)));  // 4 KB

    int tid = threadIdx.x;
    int vtile = blockIdx.x;      // 0..107
    int btile = blockIdx.y;      // 0..15
    int wid = tid >> 6, lane = tid & 63;
    int wavev = wid & 1, waveb = wid >> 1;
    int kq = lane >> 4, l15 = lane & 15;

    const float4* pA4 = (const float4*)pdBsw;
    const float4* pB4 = (const float4*)ABsw;

    f32x4 acc[3][2][2] = {};

    // LDS element offsets (ushort units)
    int aoff = (kq * 64 + wavev * 32 + l15) * 8;      // + c*2048 + vi*128
    int boff = (kq * 64 + waveb * 32 + l15) * 8;      // + bi*128

    for (int kt = 0; kt < 7; ++kt) {
        int abase = (vtile * 7 + kt) * 768;
        int bbase = (btile * 7 + kt) * 256;
        ((float4*)As)[tid]       = pA4[abase + tid];
        ((float4*)As)[tid + 256] = pA4[abase + tid + 256];
        ((float4*)As)[tid + 512] = pA4[abase + tid + 512];
        ((float4*)Bs)[tid]       = pB4[bbase + tid];
        __syncthreads();

        bf16x8 bf[2];
#pragma unroll
        for (int bi = 0; bi < 2; ++bi)
            bf[bi] = *(const bf16x8*)&Bs[boff + bi * 128];
#pragma unroll
        for (int c = 0; c < 3; ++c) {
            bf16x8 af[2];
#pragma unroll
            for (int vi = 0; vi < 2; ++vi)
                af[vi] = *(const bf16x8*)&As[aoff + c * 2048 + vi * 128];
#pragma unroll
            for (int vi = 0; vi < 2; ++vi)
#pragma unroll
                for (int bi = 0; bi < 2; ++bi)
                    acc[c][vi][bi] = __builtin_amdgcn_mfma_f32_16x16x32_bf16(
                        af[vi], bf[bi], acc[c][vi][bi], 0, 0, 0);
        }
        __syncthreads();
    }

    // store: lane holds rows v = base + (lane>>4)*4 + r, col b = base + (lane&15)
#pragma unroll
    for (int c = 0; c < 3; ++c)
#pragma unroll
        for (int vi = 0; vi < 2; ++vi)
#pragma unroll
            for (int bi = 0; bi < 2; ++bi) {
                int v = vtile * 64 + wavev * 32 + vi * 16 + (kq << 2);
                int b = btile * 64 + waveb * 32 + bi * 16 + l15;
                float* dst = outp + (size_t)b * V3 + c * NV + v;
                f32x4 a = acc[c][vi][bi];
#pragma unroll
                for (int r = 0; r < 4; ++r)
                    if (v + r < NV) dst[r] = a[r];
            }
}

// ---------------------------------------------------------------------------
// kb: blend. One block per batch b (G2 rows are block-uniform -> SGPRs).
// Thread covers 27 verts (v = tid + vt*256). Reads vph (c-planar) from the
// out region into regs, __syncthreads, j-loop FMA, in-place coalesced store.
// ---------------------------------------------------------------------------
__launch_bounds__(256, 2)
__global__ void kb(const float* __restrict__ G4, const float* __restrict__ wtsT,
                   const float* __restrict__ trans, float* __restrict__ out)
{
    int b = blockIdx.x;
    int tid = threadIdx.x;
    float* slice = out + (size_t)b * V3;

    float px[27], py[27], pz[27];
#pragma unroll
    for (int vt = 0; vt < 27; ++vt) {
        int v = tid + vt * 256;
        bool ok = v < NV;
        px[vt] = ok ? slice[0 * NV + v] : 0.0f;
        py[vt] = ok ? slice[1 * NV + v] : 0.0f;
        pz[vt] = ok ? slice[2 * NV + v] : 0.0f;
    }
    __syncthreads();   // all reads of the slice done before any write

    float ax[27], ay[27], az[27];
#pragma unroll
    for (int vt = 0; vt < 27; ++vt) { ax[vt] = 0.0f; ay[vt] = 0.0f; az[vt] = 0.0f; }

    const float* gb = G4 + b * 288;
#pragma unroll 1
    for (int j = 0; j < NJ; ++j) {
        const float* g = gb + j * 12;
        float g0 = g[0], g1 = g[1], g2 = g[2],  g3 = g[3];
        float g4 = g[4], g5 = g[5], g6 = g[6],  g7 = g[7];
        float g8 = g[8], g9 = g[9], g10 = g[10], g11 = g[11];
        const float* wrow = wtsT + j * NVP;
#pragma unroll
        for (int vt = 0; vt < 27; ++vt) {
            float w = wrow[tid + vt * 256];
            float x = px[vt], y = py[vt], z = pz[vt];
            float t0 = g0 * x + g1 * y + g2 * z + g3;
            float t1 = g4 * x + g5 * y + g6 * z + g7;
            float t2 = g8 * x + g9 * y + g10 * z + g11;
            ax[vt] += w * t0;
            ay[vt] += w * t1;
            az[vt] += w * t2;
        }
    }

    float tx = trans[b * 3 + 0], ty = trans[b * 3 + 1], tz = trans[b * 3 + 2];
#pragma unroll
    for (int vt = 0; vt < 27; ++vt) {
        int v = tid + vt * 256;
        if (v < NV) {
            slice[v * 3 + 0] = ax[vt] + tx;
            slice[v * 3 + 1] = ay[vt] + ty;
            slice[v * 3 + 2] = az[vt] + tz;
        }
    }
}

extern "C" void kernel_launch(void* const* d_in, const int* in_sizes, int n_in,
                              void* d_out, int out_size, void* d_ws, size_t ws_size,
                              hipStream_t stream)
{
    const float* pose   = (const float*)d_in[0];
    const float* betas  = (const float*)d_in[1];
    const float* trans  = (const float*)d_in[2];
    const float* vtempl = (const float*)d_in[3];
    const float* shdirs = (const float*)d_in[4];
    const float* pdirs  = (const float*)d_in[5];
    const float* Jreg   = (const float*)d_in[6];
    const float* wts    = (const float*)d_in[7];
    float* out = (float*)d_out;
    float* ws  = (float*)d_ws;

    float* Jc   = ws;                       // 792 (pad 1024)
    float* G4   = ws + 1024;                // 294912
    float* wtsT = ws + 295936;              // 165888
    __hip_bfloat16* ABsw  = (__hip_bfloat16*)(ws + 461824);   // 229376 bf16
    __hip_bfloat16* pdBsw = (__hip_bfloat16*)(ws + 576512);   // 4644864 bf16

    hipMemsetAsync(Jc, 0, NJ * 33 * sizeof(float), stream);
    hipLaunchKernelGGL(k0, dim3(NJ, 4), dim3(256), 0, stream, Jreg, vtempl, shdirs, Jc);
    hipLaunchKernelGGL(kpack, dim3(2268), dim3(256), 0, stream, pdirs, shdirs, vtempl, pdBsw);
    hipLaunchKernelGGL(kw, dim3(648), dim3(256), 0, stream, wts, wtsT);
    hipLaunchKernelGGL(k1, dim3(NB / 4), dim3(256), 0, stream,
                       pose, betas, trans, Jc, ABsw, G4, out);
    hipLaunchKernelGGL(k2g, dim3(108, 16), dim3(256), 0, stream, pdBsw, ABsw, out);
    hipLaunchKernelGGL(kb, dim3(NB), dim3(256), 0, stream, G4, wtsT, trans, out);
}

// Round 3
// 287.472 us; speedup vs baseline: 2.9065x; 2.9065x over previous
//
#include <hip/hip_runtime.h>
#include <hip/hip_bf16.h>

#define NJ 24
#define NV 6890
#define NB 1024
#define V3 (NV*3)         // 20670 floats per batch in out
#define JTR_OFF (NB*NV*3)

typedef __attribute__((ext_vector_type(8))) short bf16x8;
typedef __attribute__((ext_vector_type(4))) float f32x4;

__constant__ int c_par[NJ] = {-1,0,0,0,1,2,3,4,5,6,7,8,9,9,9,12,13,14,16,17,18,19,20,21};

// ---------------------------------------------------------------------------
// k0: fold joint regressor: Jc[j][c][s], s<10: Jreg@shapedirs, s=10: Jreg@tmpl
// ---------------------------------------------------------------------------
__global__ void k0(const float* __restrict__ Jreg, const float* __restrict__ vtempl,
                   const float* __restrict__ shdirs, float* __restrict__ Jc)
{
    int j = blockIdx.x;
    float acc[33];
#pragma unroll
    for (int i = 0; i < 33; ++i) acc[i] = 0.0f;

    for (int v = blockIdx.y * 256 + threadIdx.x; v < NV; v += 1024) {
        float r = Jreg[j * NV + v];
#pragma unroll
        for (int c = 0; c < 3; ++c) {
            acc[c * 11 + 10] += r * vtempl[v * 3 + c];
            const float* sd = &shdirs[(v * 3 + c) * 10];
#pragma unroll
            for (int s = 0; s < 10; ++s) acc[c * 11 + s] += r * sd[s];
        }
    }
#pragma unroll
    for (int i = 0; i < 33; ++i) {
        float x = acc[i];
        for (int o = 32; o > 0; o >>= 1) x += __shfl_down(x, o, 64);
        acc[i] = x;
    }
    __shared__ float red[4][33];
    int w = threadIdx.x >> 6, l = threadIdx.x & 63;
    if (l == 0) {
#pragma unroll
        for (int i = 0; i < 33; ++i) red[w][i] = acc[i];
    }
    __syncthreads();
    if (threadIdx.x < 33) {
        float s = red[0][threadIdx.x] + red[1][threadIdx.x] +
                  red[2][threadIdx.x] + red[3][threadIdx.x];
        atomicAdd(&Jc[j * 33 + threadIdx.x], s);
    }
}

// ---------------------------------------------------------------------------
// kpack: build pdB_sw (bf16), pre-swizzled to the k2g LDS image order:
//   chunk cid = (((vtile*7 + kt)*3 + c)*4 + kq)*64 + v64 ; each chunk = 8 k.
// ---------------------------------------------------------------------------
__global__ void kpack(const float* __restrict__ pdirs, const float* __restrict__ shdirs,
                      const float* __restrict__ vtempl, __hip_bfloat16* __restrict__ pdBsw)
{
    int cid = blockIdx.x * 256 + threadIdx.x;   // < 580608
    int v64 = cid & 63;
    int t = cid >> 6;
    int kq = t & 3; t >>= 2;
    int c = t % 3; t /= 3;
    int kt = t % 7;
    int vt = t / 7;
    int v = vt * 64 + v64;

    ushort tmp[8] __attribute__((aligned(16)));
#pragma unroll
    for (int j = 0; j < 8; ++j) {
        int k = kt * 32 + kq * 8 + j;
        float val = 0.0f;
        if (v < NV) {
            if (k < 207)       val = pdirs[(v * 3 + c) * 207 + k];
            else if (k < 217)  val = shdirs[(v * 3 + c) * 10 + (k - 207)];
            else if (k == 217) val = vtempl[v * 3 + c];
        }
        __hip_bfloat16 h = __float2bfloat16(val);
        tmp[j] = *(ushort*)&h;
    }
    ((float4*)pdBsw)[cid] = *(const float4*)tmp;
}

// ---------------------------------------------------------------------------
// k1: Rodrigues, A (bf16, swizzled), th_j, kinematic chain, G4[b][j][3][4],
//     th_jtr. One wave per batch, 4 batches/block.
// ABsw chunk: ((btile*7 + kt)*4 + kq)*64 + b64, 8 k each.
// ---------------------------------------------------------------------------
__device__ __forceinline__ void writeA(__hip_bfloat16* ABsw, int b, int k, float val)
{
    int btile = b >> 6, b6 = b & 63, kt = k >> 5, kq = (k >> 3) & 3, j = k & 7;
    __hip_bfloat16 h = __float2bfloat16(val);
    ABsw[((((btile * 7) + kt) * 4 + kq) * 64 + b6) * 8 + j] = h;
}

__global__ void k1(const float* __restrict__ pose, const float* __restrict__ betas,
                   const float* __restrict__ trans, const float* __restrict__ Jc,
                   __hip_bfloat16* __restrict__ ABsw, float* __restrict__ G4,
                   float* __restrict__ out)
{
    __shared__ float rots[4][NJ][9];
    __shared__ float thj [4][NJ][3];
    __shared__ float res [4][NJ][16];

    int w = threadIdx.x >> 6;
    int l = threadIdx.x & 63;
    int b = blockIdx.x * 4 + w;

    if (l < NJ) {
        int j = l;
        float ax = pose[b * 72 + j * 3 + 0];
        float ay = pose[b * 72 + j * 3 + 1];
        float az = pose[b * 72 + j * 3 + 2];
        float theta = sqrtf(ax * ax + ay * ay + az * az + 1e-8f);
        float inv = 1.0f / theta;
        float kx = ax * inv, ky = ay * inv, kz = az * inv;
        float c = cosf(theta), s = sinf(theta), mc = 1.0f - c;
        float R[9];
        R[0] = 1.0f - mc * (ky * ky + kz * kz);
        R[1] = -s * kz + mc * (kx * ky);
        R[2] =  s * ky + mc * (kx * kz);
        R[3] =  s * kz + mc * (kx * ky);
        R[4] = 1.0f - mc * (kx * kx + kz * kz);
        R[5] = -s * kx + mc * (ky * kz);
        R[6] = -s * ky + mc * (kx * kz);
        R[7] =  s * kx + mc * (ky * kz);
        R[8] = 1.0f - mc * (kx * kx + ky * ky);
#pragma unroll
        for (int e = 0; e < 9; ++e) rots[w][j][e] = R[e];
        if (j >= 1) {
            int base = (j - 1) * 9;
#pragma unroll
            for (int e = 0; e < 9; ++e) {
                float val = R[e] - ((e == 0 || e == 4 || e == 8) ? 1.0f : 0.0f);
                writeA(ABsw, b, base + e, val);
            }
        }
#pragma unroll
        for (int c3 = 0; c3 < 3; ++c3) {
            float acc = Jc[(j * 3 + c3) * 11 + 10];
#pragma unroll
            for (int s10 = 0; s10 < 10; ++s10)
                acc += Jc[(j * 3 + c3) * 11 + s10] * betas[b * 10 + s10];
            thj[w][j][c3] = acc;
        }
    } else if (l < 41) {
        int k = 207 + (l - 24);
        float val;
        if (l < 34)       val = betas[b * 10 + (l - 24)];
        else if (l == 34) val = 1.0f;
        else              val = 0.0f;
        writeA(ABsw, b, k, val);
    }
    __syncthreads();

    if (l < 16) {
        int m = l >> 2, n = l & 3;
        float v;
        if (m < 3) v = (n < 3) ? rots[w][0][m * 3 + n] : thj[w][0][m];
        else       v = (n == 3) ? 1.0f : 0.0f;
        res[w][0][l] = v;
    }
    __syncthreads();
#pragma unroll
    for (int i = 1; i < NJ; ++i) {
        int p = c_par[i];
        if (l < 16) {
            int m = l >> 2, n = l & 3;
            float acc = 0.0f;
#pragma unroll
            for (int k3 = 0; k3 < 3; ++k3) {
                float relkn = (n < 3) ? rots[w][i][k3 * 3 + n]
                                      : (thj[w][i][k3] - thj[w][p][k3]);
                acc += res[w][p][m * 4 + k3] * relkn;
            }
            if (n == 3) acc += res[w][p][m * 4 + 3];
            res[w][i][l] = acc;
        }
        __syncthreads();
    }

    if (l < NJ) {
        int j = l;
#pragma unroll
        for (int c3 = 0; c3 < 3; ++c3)
            out[JTR_OFF + b * 72 + j * 3 + c3] = res[w][j][c3 * 4 + 3] + trans[b * 3 + c3];
    }
    // G2[b][j][m][n]: cols 0..2 = G, col 3 = G.t - G.R @ thj
    for (int k = l; k < 288; k += 64) {
        int j = k / 12, m = (k % 12) >> 2, n = k & 3;
        float v;
        if (n < 3) v = res[w][j][m * 4 + n];
        else v = res[w][j][m * 4 + 3] - (res[w][j][m * 4 + 0] * thj[w][j][0] +
                                         res[w][j][m * 4 + 1] * thj[w][j][1] +
                                         res[w][j][m * 4 + 2] * thj[w][j][2]);
        G4[b * 288 + k] = v;
    }
}

// ---------------------------------------------------------------------------
// k2g: MFMA GEMM, roles: A = batches (M), B = verts (N)  ->  C row=b, col=v.
// Block: 64b x 64v x 3c, 4 waves (2x2), K-loop 7 x 32, mfma 16x16x32 bf16.
// Stores v_posed DIRECTLY into final interleaved layout out[b*V3 + v*3 + c]:
// per store instr 16 lanes cover 16 consecutive v at stride 12B = dense 192B.
// ---------------------------------------------------------------------------
__launch_bounds__(256, 3)
__global__ void k2g(const __hip_bfloat16* __restrict__ pdBsw,
                    const __hip_bfloat16* __restrict__ ABsw,
                    float* __restrict__ outp)
{
    __shared__ ushort As[3 * 4 * 64 * 8] __attribute__((aligned(16)));  // verts, 12 KB
    __shared__ ushort Bs[4 * 64 * 8]     __attribute__((aligned(16)));  // batch, 4 KB

    int tid = threadIdx.x;
    int vtile = blockIdx.x;      // 0..107
    int btile = blockIdx.y;      // 0..15
    int wid = tid >> 6, lane = tid & 63;
    int waveb = wid & 1, wavev = wid >> 1;
    int kq = lane >> 4, l15 = lane & 15;

    const float4* pA4 = (const float4*)pdBsw;
    const float4* pB4 = (const float4*)ABsw;

    f32x4 acc[3][2][2] = {};   // [c][mi=b-sub][ni=v-sub]

    int aoff = (kq * 64 + waveb * 32 + l15) * 8;      // batch frag (from Bs) + mi*128
    int boff = (kq * 64 + wavev * 32 + l15) * 8;      // vert frag (from As) + ni*128 + c*2048

    for (int kt = 0; kt < 7; ++kt) {
        int abase = (vtile * 7 + kt) * 768;
        int bbase = (btile * 7 + kt) * 256;
        ((float4*)As)[tid]       = pA4[abase + tid];
        ((float4*)As)[tid + 256] = pA4[abase + tid + 256];
        ((float4*)As)[tid + 512] = pA4[abase + tid + 512];
        ((float4*)Bs)[tid]       = pB4[bbase + tid];
        __syncthreads();

        bf16x8 af[2];
#pragma unroll
        for (int mi = 0; mi < 2; ++mi)
            af[mi] = *(const bf16x8*)&Bs[aoff + mi * 128];
#pragma unroll
        for (int c = 0; c < 3; ++c) {
            bf16x8 bfr[2];
#pragma unroll
            for (int ni = 0; ni < 2; ++ni)
                bfr[ni] = *(const bf16x8*)&As[boff + c * 2048 + ni * 128];
#pragma unroll
            for (int mi = 0; mi < 2; ++mi)
#pragma unroll
                for (int ni = 0; ni < 2; ++ni)
                    acc[c][mi][ni] = __builtin_amdgcn_mfma_f32_16x16x32_bf16(
                        af[mi], bfr[ni], acc[c][mi][ni], 0, 0, 0);
        }
        __syncthreads();
    }

    // C/D: row (=batch) = kq*4 + r, col (=vert) = l15 within each 16x16 subtile
#pragma unroll
    for (int c = 0; c < 3; ++c)
#pragma unroll
        for (int mi = 0; mi < 2; ++mi)
#pragma unroll
            for (int ni = 0; ni < 2; ++ni) {
                int v = vtile * 64 + wavev * 32 + ni * 16 + l15;
                int b = btile * 64 + waveb * 32 + mi * 16 + (kq << 2);
                f32x4 a = acc[c][mi][ni];
                if (v < NV) {
#pragma unroll
                    for (int r = 0; r < 4; ++r)
                        outp[(size_t)(b + r) * V3 + v * 3 + c] = a[r];
                }
            }
}

// ---------------------------------------------------------------------------
// kb: blend, in place. Grid 27 vtiles x 128 bgroups. Thread = one vertex:
// 24 weights in regs (6 x float4), loop 8 batches: read own [b][v][0..2]
// (dense), G2 via block-uniform s_loads, 24-joint FMA, write back in place.
// Read set == write set per thread -> no races, no __syncthreads.
// ---------------------------------------------------------------------------
__launch_bounds__(256, 4)
__global__ void kb(const float* __restrict__ G4, const float* __restrict__ wts,
                   const float* __restrict__ trans, float* __restrict__ out)
{
    int v = blockIdx.x * 256 + threadIdx.x;
    if (v >= NV) return;
    int bg = blockIdx.y;             // 0..127

    float w[NJ];
    const float4* wv = (const float4*)(wts + (size_t)v * NJ);
#pragma unroll
    for (int q = 0; q < 6; ++q) {
        float4 t = wv[q];
        w[q * 4 + 0] = t.x; w[q * 4 + 1] = t.y;
        w[q * 4 + 2] = t.z; w[q * 4 + 3] = t.w;
    }

#pragma unroll 1
    for (int bi = 0; bi < 8; ++bi) {
        int b = bg * 8 + bi;
        float* p = out + (size_t)b * V3 + v * 3;
        float x = p[0], y = p[1], z = p[2];
        const float* g = G4 + b * 288;     // block-uniform -> s_load
        float ax = 0.0f, ay = 0.0f, az = 0.0f;
#pragma unroll
        for (int j = 0; j < NJ; ++j) {
            const float* gj = g + j * 12;
            float t0 = gj[0] * x + gj[1] * y + gj[2]  * z + gj[3];
            float t1 = gj[4] * x + gj[5] * y + gj[6]  * z + gj[7];
            float t2 = gj[8] * x + gj[9] * y + gj[10] * z + gj[11];
            ax += w[j] * t0;
            ay += w[j] * t1;
            az += w[j] * t2;
        }
        p[0] = ax + trans[b * 3 + 0];
        p[1] = ay + trans[b * 3 + 1];
        p[2] = az + trans[b * 3 + 2];
    }
}

extern "C" void kernel_launch(void* const* d_in, const int* in_sizes, int n_in,
                              void* d_out, int out_size, void* d_ws, size_t ws_size,
                              hipStream_t stream)
{
    const float* pose   = (const float*)d_in[0];
    const float* betas  = (const float*)d_in[1];
    const float* trans  = (const float*)d_in[2];
    const float* vtempl = (const float*)d_in[3];
    const float* shdirs = (const float*)d_in[4];
    const float* pdirs  = (const float*)d_in[5];
    const float* Jreg   = (const float*)d_in[6];
    const float* wts    = (const float*)d_in[7];
    float* out = (float*)d_out;
    float* ws  = (float*)d_ws;

    float* Jc   = ws;                       // 792 (pad 1024)
    float* G4   = ws + 1024;                // 294912 floats
    __hip_bfloat16* ABsw  = (__hip_bfloat16*)(ws + 295936);   // 229376 bf16
    __hip_bfloat16* pdBsw = (__hip_bfloat16*)(ws + 410624);   // 4644864 bf16

    hipMemsetAsync(Jc, 0, NJ * 33 * sizeof(float), stream);
    hipLaunchKernelGGL(k0, dim3(NJ, 4), dim3(256), 0, stream, Jreg, vtempl, shdirs, Jc);
    hipLaunchKernelGGL(kpack, dim3(2268), dim3(256), 0, stream, pdirs, shdirs, vtempl, pdBsw);
    hipLaunchKernelGGL(k1, dim3(NB / 4), dim3(256), 0, stream,
                       pose, betas, trans, Jc, ABsw, G4, out);
    hipLaunchKernelGGL(k2g, dim3(108, 16), dim3(256), 0, stream, pdBsw, ABsw, out);
    hipLaunchKernelGGL(kb, dim3(27, 128), dim3(256), 0, stream, G4, wts, trans, out);
}

// Round 4
// 214.883 us; speedup vs baseline: 3.8884x; 1.3378x over previous
//
#include <hip/hip_runtime.h>
#include <hip/hip_bf16.h>

#define NJ 24
#define NV 6890
#define NB 1024
#define V3 (NV*3)         // 20670 floats per batch in out
#define JTR_OFF (NB*NV*3)

typedef __attribute__((ext_vector_type(8))) short bf16x8;
typedef __attribute__((ext_vector_type(4))) float f32x4;

__constant__ int c_par[NJ] = {-1,0,0,0,1,2,3,4,5,6,7,8,9,9,9,12,13,14,16,17,18,19,20,21};

// ---------------------------------------------------------------------------
// k0: fold joint regressor: Jc[j][c][s], s<10: Jreg@shapedirs, s=10: Jreg@tmpl
// ---------------------------------------------------------------------------
__global__ void k0(const float* __restrict__ Jreg, const float* __restrict__ vtempl,
                   const float* __restrict__ shdirs, float* __restrict__ Jc)
{
    int j = blockIdx.x;
    float acc[33];
#pragma unroll
    for (int i = 0; i < 33; ++i) acc[i] = 0.0f;

    for (int v = blockIdx.y * 256 + threadIdx.x; v < NV; v += 1024) {
        float r = Jreg[j * NV + v];
#pragma unroll
        for (int c = 0; c < 3; ++c) {
            acc[c * 11 + 10] += r * vtempl[v * 3 + c];
            const float* sd = &shdirs[(v * 3 + c) * 10];
#pragma unroll
            for (int s = 0; s < 10; ++s) acc[c * 11 + s] += r * sd[s];
        }
    }
#pragma unroll
    for (int i = 0; i < 33; ++i) {
        float x = acc[i];
        for (int o = 32; o > 0; o >>= 1) x += __shfl_down(x, o, 64);
        acc[i] = x;
    }
    __shared__ float red[4][33];
    int w = threadIdx.x >> 6, l = threadIdx.x & 63;
    if (l == 0) {
#pragma unroll
        for (int i = 0; i < 33; ++i) red[w][i] = acc[i];
    }
    __syncthreads();
    if (threadIdx.x < 33) {
        float s = red[0][threadIdx.x] + red[1][threadIdx.x] +
                  red[2][threadIdx.x] + red[3][threadIdx.x];
        atomicAdd(&Jc[j * 33 + threadIdx.x], s);
    }
}

// ---------------------------------------------------------------------------
// kpack: build pdB_sw (bf16), pre-swizzled to the k2g LDS image order:
//   chunk cid = (((vtile*7 + kt)*3 + c)*4 + kq)*64 + v64 ; each chunk = 8 k.
// ---------------------------------------------------------------------------
__global__ void kpack(const float* __restrict__ pdirs, const float* __restrict__ shdirs,
                      const float* __restrict__ vtempl, __hip_bfloat16* __restrict__ pdBsw)
{
    int cid = blockIdx.x * 256 + threadIdx.x;   // < 580608
    int v64 = cid & 63;
    int t = cid >> 6;
    int kq = t & 3; t >>= 2;
    int c = t % 3; t /= 3;
    int kt = t % 7;
    int vt = t / 7;
    int v = vt * 64 + v64;

    ushort tmp[8] __attribute__((aligned(16)));
#pragma unroll
    for (int j = 0; j < 8; ++j) {
        int k = kt * 32 + kq * 8 + j;
        float val = 0.0f;
        if (v < NV) {
            if (k < 207)       val = pdirs[(v * 3 + c) * 207 + k];
            else if (k < 217)  val = shdirs[(v * 3 + c) * 10 + (k - 207)];
            else if (k == 217) val = vtempl[v * 3 + c];
        }
        __hip_bfloat16 h = __float2bfloat16(val);
        tmp[j] = *(ushort*)&h;
    }
    ((float4*)pdBsw)[cid] = *(const float4*)tmp;
}

// ---------------------------------------------------------------------------
// kwB: weights -> bf16 B-operand swizzle. chunk = (vtile*4 + kq)*64 + v64,
// 8 j each, K=32 (24 j + 8 zero pad).  27648 chunks.
// ---------------------------------------------------------------------------
__global__ void kwB(const float* __restrict__ wts, __hip_bfloat16* __restrict__ wtsB)
{
    int t = blockIdx.x * 256 + threadIdx.x;     // < 27648
    int v64 = t & 63;
    int kq = (t >> 6) & 3;
    int vt = t >> 8;
    int v = vt * 64 + v64;

    ushort tmp[8] __attribute__((aligned(16)));
#pragma unroll
    for (int j8 = 0; j8 < 8; ++j8) {
        int j = kq * 8 + j8;
        float val = (v < NV && j < NJ) ? wts[v * NJ + j] : 0.0f;
        __hip_bfloat16 h = __float2bfloat16(val);
        tmp[j8] = *(ushort*)&h;
    }
    ((float4*)wtsB)[t] = *(const float4*)tmp;
}

// ---------------------------------------------------------------------------
// k1: Rodrigues, A (bf16, swizzled), th_j, kinematic chain, G2B (bf16,
// A-operand swizzled, 12 components), th_jtr. One wave/batch, 4 batches/block.
// ABsw chunk: ((btile*7 + kt)*4 + kq)*64 + b64, 8 k each.
// G2B[mc] chunk: ((btile*4 + jq)*64 + b64)*8 + j7, mc stride 32768 elements.
// ---------------------------------------------------------------------------
__device__ __forceinline__ void writeA(__hip_bfloat16* ABsw, int b, int k, float val)
{
    int btile = b >> 6, b6 = b & 63, kt = k >> 5, kq = (k >> 3) & 3, j = k & 7;
    __hip_bfloat16 h = __float2bfloat16(val);
    ABsw[((((btile * 7) + kt) * 4 + kq) * 64 + b6) * 8 + j] = h;
}

__global__ void k1(const float* __restrict__ pose, const float* __restrict__ betas,
                   const float* __restrict__ trans, const float* __restrict__ Jc,
                   __hip_bfloat16* __restrict__ ABsw, __hip_bfloat16* __restrict__ G2B,
                   float* __restrict__ out)
{
    __shared__ float rots[4][NJ][9];
    __shared__ float thj [4][NJ][3];
    __shared__ float res [4][NJ][16];

    int w = threadIdx.x >> 6;
    int l = threadIdx.x & 63;
    int b = blockIdx.x * 4 + w;

    if (l < NJ) {
        int j = l;
        float ax = pose[b * 72 + j * 3 + 0];
        float ay = pose[b * 72 + j * 3 + 1];
        float az = pose[b * 72 + j * 3 + 2];
        float theta = sqrtf(ax * ax + ay * ay + az * az + 1e-8f);
        float inv = 1.0f / theta;
        float kx = ax * inv, ky = ay * inv, kz = az * inv;
        float c = cosf(theta), s = sinf(theta), mc = 1.0f - c;
        float R[9];
        R[0] = 1.0f - mc * (ky * ky + kz * kz);
        R[1] = -s * kz + mc * (kx * ky);
        R[2] =  s * ky + mc * (kx * kz);
        R[3] =  s * kz + mc * (kx * ky);
        R[4] = 1.0f - mc * (kx * kx + kz * kz);
        R[5] = -s * kx + mc * (ky * kz);
        R[6] = -s * ky + mc * (kx * kz);
        R[7] =  s * kx + mc * (ky * kz);
        R[8] = 1.0f - mc * (kx * kx + ky * ky);
#pragma unroll
        for (int e = 0; e < 9; ++e) rots[w][j][e] = R[e];
        if (j >= 1) {
            int base = (j - 1) * 9;
#pragma unroll
            for (int e = 0; e < 9; ++e) {
                float val = R[e] - ((e == 0 || e == 4 || e == 8) ? 1.0f : 0.0f);
                writeA(ABsw, b, base + e, val);
            }
        }
#pragma unroll
        for (int c3 = 0; c3 < 3; ++c3) {
            float acc = Jc[(j * 3 + c3) * 11 + 10];
#pragma unroll
            for (int s10 = 0; s10 < 10; ++s10)
                acc += Jc[(j * 3 + c3) * 11 + s10] * betas[b * 10 + s10];
            thj[w][j][c3] = acc;
        }
    } else if (l < 41) {
        int k = 207 + (l - 24);
        float val;
        if (l < 34)       val = betas[b * 10 + (l - 24)];
        else if (l == 34) val = 1.0f;
        else              val = 0.0f;
        writeA(ABsw, b, k, val);
    }
    __syncthreads();

    if (l < 16) {
        int m = l >> 2, n = l & 3;
        float v;
        if (m < 3) v = (n < 3) ? rots[w][0][m * 3 + n] : thj[w][0][m];
        else       v = (n == 3) ? 1.0f : 0.0f;
        res[w][0][l] = v;
    }
    __syncthreads();
#pragma unroll
    for (int i = 1; i < NJ; ++i) {
        int p = c_par[i];
        if (l < 16) {
            int m = l >> 2, n = l & 3;
            float acc = 0.0f;
#pragma unroll
            for (int k3 = 0; k3 < 3; ++k3) {
                float relkn = (n < 3) ? rots[w][i][k3 * 3 + n]
                                      : (thj[w][i][k3] - thj[w][p][k3]);
                acc += res[w][p][m * 4 + k3] * relkn;
            }
            if (n == 3) acc += res[w][p][m * 4 + 3];
            res[w][i][l] = acc;
        }
        __syncthreads();
    }

    if (l < NJ) {
        int j = l;
#pragma unroll
        for (int c3 = 0; c3 < 3; ++c3)
            out[JTR_OFF + b * 72 + j * 3 + c3] = res[w][j][c3 * 4 + 3] + trans[b * 3 + c3];
    }
    // G2B: 12 components mc = m*4+n, K=32 (j=24..31 zero), bf16 A-operand swizzle
    for (int k = l; k < 384; k += 64) {
        int mc = k >> 5, j = k & 31;
        int m = mc >> 2, n = mc & 3;
        float v = 0.0f;
        if (j < NJ) {
            if (n < 3) v = res[w][j][m * 4 + n];
            else v = res[w][j][m * 4 + 3] - (res[w][j][m * 4 + 0] * thj[w][j][0] +
                                             res[w][j][m * 4 + 1] * thj[w][j][1] +
                                             res[w][j][m * 4 + 2] * thj[w][j][2]);
        }
        __hip_bfloat16 h = __float2bfloat16(v);
        G2B[mc * 32768 + ((((b >> 6) * 4) + (j >> 3)) * 64 + (b & 63)) * 8 + (j & 7)] = h;
    }
}

// ---------------------------------------------------------------------------
// k2g: fused pose-GEMM + MFMA blend.  A = batches (M), B = verts (N).
// Block: 64b x 64v x 3c, 4 waves (2x2), K-loop 7 x 32, mfma 16x16x32 bf16.
// Epilogue: T[mc][b][v] = G2B[mc] @ wtsB^T  (12 mini-MFMAs per subtile pair,
// frags loaded straight from global/L2), then vert_m = T_m0*x+T_m1*y+T_m2*z
// + T_m3 + trans, stored dense into out[b*V3 + v*3 + m].
// ---------------------------------------------------------------------------
__launch_bounds__(256, 3)
__global__ void k2g(const __hip_bfloat16* __restrict__ pdBsw,
                    const __hip_bfloat16* __restrict__ ABsw,
                    const __hip_bfloat16* __restrict__ G2B,
                    const __hip_bfloat16* __restrict__ wtsB,
                    const float* __restrict__ trans,
                    float* __restrict__ outp)
{
    __shared__ ushort As[3 * 4 * 64 * 8] __attribute__((aligned(16)));  // verts, 12 KB
    __shared__ ushort Bs[4 * 64 * 8]     __attribute__((aligned(16)));  // batch, 4 KB

    int tid = threadIdx.x;
    int vtile = blockIdx.x;      // 0..107
    int btile = blockIdx.y;      // 0..15
    int wid = tid >> 6, lane = tid & 63;
    int waveb = wid & 1, wavev = wid >> 1;
    int kq = lane >> 4, l15 = lane & 15;

    const float4* pA4 = (const float4*)pdBsw;
    const float4* pB4 = (const float4*)ABsw;

    f32x4 acc[3][2][2] = {};   // [c][mi=b-sub][ni=v-sub]

    int aoff = (kq * 64 + waveb * 32 + l15) * 8;      // batch frag (from Bs) + mi*128
    int boff = (kq * 64 + wavev * 32 + l15) * 8;      // vert frag (from As) + ni*128 + c*2048

    for (int kt = 0; kt < 7; ++kt) {
        int abase = (vtile * 7 + kt) * 768;
        int bbase = (btile * 7 + kt) * 256;
        ((float4*)As)[tid]       = pA4[abase + tid];
        ((float4*)As)[tid + 256] = pA4[abase + tid + 256];
        ((float4*)As)[tid + 512] = pA4[abase + tid + 512];
        ((float4*)Bs)[tid]       = pB4[bbase + tid];
        __syncthreads();

        bf16x8 af[2];
#pragma unroll
        for (int mi = 0; mi < 2; ++mi)
            af[mi] = *(const bf16x8*)&Bs[aoff + mi * 128];
#pragma unroll
        for (int c = 0; c < 3; ++c) {
            bf16x8 bfr[2];
#pragma unroll
            for (int ni = 0; ni < 2; ++ni)
                bfr[ni] = *(const bf16x8*)&As[boff + c * 2048 + ni * 128];
#pragma unroll
            for (int mi = 0; mi < 2; ++mi)
#pragma unroll
                for (int ni = 0; ni < 2; ++ni)
                    acc[c][mi][ni] = __builtin_amdgcn_mfma_f32_16x16x32_bf16(
                        af[mi], bfr[ni], acc[c][mi][ni], 0, 0, 0);
        }
        __syncthreads();
    }

    // ---- blend epilogue ----
    // wts B-frags (col = v), one per ni — same for all 12 components
    bf16x8 wf[2];
#pragma unroll
    for (int ni = 0; ni < 2; ++ni)
        wf[ni] = *(const bf16x8*)&wtsB[(((vtile * 4 + kq) * 64) +
                                        wavev * 32 + ni * 16 + l15) * 8];

    int bframe = ((btile * 4 + kq) * 64 + waveb * 32 + l15) * 8;  // + mi*128

#pragma unroll
    for (int m = 0; m < 3; ++m) {
#pragma unroll
        for (int mi = 0; mi < 2; ++mi) {
            f32x4 T[4][2] = {};
#pragma unroll
            for (int c4 = 0; c4 < 4; ++c4) {
                int mc = m * 4 + c4;
                bf16x8 gf = *(const bf16x8*)&G2B[mc * 32768 + bframe + mi * 128];
#pragma unroll
                for (int ni = 0; ni < 2; ++ni)
                    T[c4][ni] = __builtin_amdgcn_mfma_f32_16x16x32_bf16(
                        gf, wf[ni], T[c4][ni], 0, 0, 0);
            }
#pragma unroll
            for (int ni = 0; ni < 2; ++ni) {
                int v = vtile * 64 + wavev * 32 + ni * 16 + l15;
                if (v < NV) {
#pragma unroll
                    for (int r = 0; r < 4; ++r) {
                        int b = btile * 64 + waveb * 32 + mi * 16 + (kq << 2) + r;
                        float x = acc[0][mi][ni][r];
                        float y = acc[1][mi][ni][r];
                        float z = acc[2][mi][ni][r];
                        float val = T[3][ni][r] + T[0][ni][r] * x +
                                    T[1][ni][r] * y + T[2][ni][r] * z +
                                    trans[b * 3 + m];
                        outp[(size_t)b * V3 + v * 3 + m] = val;
                    }
                }
            }
        }
    }
}

extern "C" void kernel_launch(void* const* d_in, const int* in_sizes, int n_in,
                              void* d_out, int out_size, void* d_ws, size_t ws_size,
                              hipStream_t stream)
{
    const float* pose   = (const float*)d_in[0];
    const float* betas  = (const float*)d_in[1];
    const float* trans  = (const float*)d_in[2];
    const float* vtempl = (const float*)d_in[3];
    const float* shdirs = (const float*)d_in[4];
    const float* pdirs  = (const float*)d_in[5];
    const float* Jreg   = (const float*)d_in[6];
    const float* wts    = (const float*)d_in[7];
    float* out = (float*)d_out;
    char* ws = (char*)d_ws;

    float* Jc              = (float*)(ws);                      // 792 fl (4 KB)
    __hip_bfloat16* ABsw   = (__hip_bfloat16*)(ws + 4096);      // 229376 bf16
    __hip_bfloat16* G2B    = (__hip_bfloat16*)(ws + 462848);    // 393216 bf16
    __hip_bfloat16* wtsB   = (__hip_bfloat16*)(ws + 1249280);   // 221184 bf16
    __hip_bfloat16* pdBsw  = (__hip_bfloat16*)(ws + 1691648);   // 4644864 bf16

    hipMemsetAsync(Jc, 0, NJ * 33 * sizeof(float), stream);
    hipLaunchKernelGGL(k0, dim3(NJ, 4), dim3(256), 0, stream, Jreg, vtempl, shdirs, Jc);
    hipLaunchKernelGGL(kpack, dim3(2268), dim3(256), 0, stream, pdirs, shdirs, vtempl, pdBsw);
    hipLaunchKernelGGL(kwB, dim3(108), dim3(256), 0, stream, wts, wtsB);
    hipLaunchKernelGGL(k1, dim3(NB / 4), dim3(256), 0, stream,
                       pose, betas, trans, Jc, ABsw, G2B, out);
    hipLaunchKernelGGL(k2g, dim3(108, 16), dim3(256), 0, stream,
                       pdBsw, ABsw, G2B, wtsB, trans, out);
}